// Round 1
// baseline (3728.217 us; speedup 1.0000x reference)
//
#include <hip/hip_runtime.h>

// GCN 2-layer: N=250000 nodes, E=4000000 edges, 18 -> 16 -> 1
// Inputs: x[N,18] f32, edge_index[2,E] int32, W1[18,16], b1[16], W2[16,1], b2[1]
// Output: [N,1] f32
//
// Restructure: out[d] = dis[d] * sum_{src->d} (h[src]*dis[src]) + self + bias
// so we scale at source once, scatter-add raw, scale at dest once.
// Self-loop contribution folded into combine (agg[n] + hs[n]).

#define TPB 256

__global__ void deg_kernel(const int* __restrict__ dst, float* __restrict__ deg, int E) {
    int e = blockIdx.x * blockDim.x + threadIdx.x;
    if (e < E) unsafeAtomicAdd(&deg[dst[e]], 1.0f);
}

__global__ void dis_kernel(float* __restrict__ deg, int N) {
    int n = blockIdx.x * blockDim.x + threadIdx.x;
    if (n < N) deg[n] = rsqrtf(deg[n] + 1.0f);  // +1 for self-loop
}

// h1[n,f] = (sum_k x[n,k]*W1[k,f]) * dis[n]
__global__ void h1_kernel(const float* __restrict__ x, const float* __restrict__ W1,
                          const float* __restrict__ dis, float* __restrict__ hs1, int N) {
    __shared__ float w[18 * 16];
    for (int i = threadIdx.x; i < 18 * 16; i += blockDim.x) w[i] = W1[i];
    __syncthreads();
    int n = blockIdx.x * blockDim.x + threadIdx.x;
    if (n >= N) return;
    float xv[18];
#pragma unroll
    for (int k = 0; k < 18; k++) xv[k] = x[n * 18 + k];
    float d = dis[n];
    float acc[16];
#pragma unroll
    for (int f = 0; f < 16; f++) acc[f] = 0.0f;
#pragma unroll
    for (int k = 0; k < 18; k++) {
        float xk = xv[k];
#pragma unroll
        for (int f = 0; f < 16; f++) acc[f] = fmaf(xk, w[k * 16 + f], acc[f]);
    }
    float4* out = (float4*)(hs1 + (size_t)n * 16);
#pragma unroll
    for (int q = 0; q < 4; q++) {
        float4 v;
        v.x = acc[q * 4 + 0] * d;
        v.y = acc[q * 4 + 1] * d;
        v.z = acc[q * 4 + 2] * d;
        v.w = acc[q * 4 + 3] * d;
        out[q] = v;
    }
}

// agg1[dst,f] += hs1[src,f], 16 features per edge
__global__ void scatter1_kernel(const int* __restrict__ src, const int* __restrict__ dst,
                                const float* __restrict__ hs1, float* __restrict__ agg1, int E) {
    int e = blockIdx.x * blockDim.x + threadIdx.x;
    if (e >= E) return;
    int s = src[e], d = dst[e];
    const float4* hp = (const float4*)(hs1 + (size_t)s * 16);
    float4 v0 = hp[0], v1 = hp[1], v2 = hp[2], v3 = hp[3];
    float* out = agg1 + (size_t)d * 16;
    unsafeAtomicAdd(out + 0, v0.x);
    unsafeAtomicAdd(out + 1, v0.y);
    unsafeAtomicAdd(out + 2, v0.z);
    unsafeAtomicAdd(out + 3, v0.w);
    unsafeAtomicAdd(out + 4, v1.x);
    unsafeAtomicAdd(out + 5, v1.y);
    unsafeAtomicAdd(out + 6, v1.z);
    unsafeAtomicAdd(out + 7, v1.w);
    unsafeAtomicAdd(out + 8, v2.x);
    unsafeAtomicAdd(out + 9, v2.y);
    unsafeAtomicAdd(out + 10, v2.z);
    unsafeAtomicAdd(out + 11, v2.w);
    unsafeAtomicAdd(out + 12, v3.x);
    unsafeAtomicAdd(out + 13, v3.y);
    unsafeAtomicAdd(out + 14, v3.z);
    unsafeAtomicAdd(out + 15, v3.w);
}

// relu(dis*(agg1+hs1)+b1) @ W2, scaled by dis -> hs2[n]
__global__ void combine1_kernel(const float* __restrict__ agg1, const float* __restrict__ hs1,
                                const float* __restrict__ dis, const float* __restrict__ b1,
                                const float* __restrict__ W2, float* __restrict__ hs2, int N) {
    __shared__ float sb1[16], sw2[16];
    if (threadIdx.x < 16) {
        sb1[threadIdx.x] = b1[threadIdx.x];
        sw2[threadIdx.x] = W2[threadIdx.x];
    }
    __syncthreads();
    int n = blockIdx.x * blockDim.x + threadIdx.x;
    if (n >= N) return;
    float d = dis[n];
    const float4* ap = (const float4*)(agg1 + (size_t)n * 16);
    const float4* hp = (const float4*)(hs1 + (size_t)n * 16);
    float h2 = 0.0f;
#pragma unroll
    for (int q = 0; q < 4; q++) {
        float4 a = ap[q];
        float4 h = hp[q];
        float v0 = fmaxf(d * (a.x + h.x) + sb1[q * 4 + 0], 0.0f);
        float v1 = fmaxf(d * (a.y + h.y) + sb1[q * 4 + 1], 0.0f);
        float v2 = fmaxf(d * (a.z + h.z) + sb1[q * 4 + 2], 0.0f);
        float v3 = fmaxf(d * (a.w + h.w) + sb1[q * 4 + 3], 0.0f);
        h2 = fmaf(v0, sw2[q * 4 + 0], h2);
        h2 = fmaf(v1, sw2[q * 4 + 1], h2);
        h2 = fmaf(v2, sw2[q * 4 + 2], h2);
        h2 = fmaf(v3, sw2[q * 4 + 3], h2);
    }
    hs2[n] = h2 * d;
}

__global__ void scatter2_kernel(const int* __restrict__ src, const int* __restrict__ dst,
                                const float* __restrict__ hs2, float* __restrict__ agg2, int E) {
    int e = blockIdx.x * blockDim.x + threadIdx.x;
    if (e >= E) return;
    unsafeAtomicAdd(&agg2[dst[e]], hs2[src[e]]);
}

__global__ void combine2_kernel(const float* __restrict__ agg2, const float* __restrict__ hs2,
                                const float* __restrict__ dis, const float* __restrict__ b2,
                                float* __restrict__ out, int N) {
    int n = blockIdx.x * blockDim.x + threadIdx.x;
    if (n >= N) return;
    out[n] = dis[n] * (agg2[n] + hs2[n]) + b2[0];
}

extern "C" void kernel_launch(void* const* d_in, const int* in_sizes, int n_in,
                              void* d_out, int out_size, void* d_ws, size_t ws_size,
                              hipStream_t stream) {
    const float* x = (const float*)d_in[0];
    const int* edge_index = (const int*)d_in[1];
    const float* W1 = (const float*)d_in[2];
    const float* b1 = (const float*)d_in[3];
    const float* W2 = (const float*)d_in[4];
    const float* b2 = (const float*)d_in[5];
    float* out = (float*)d_out;

    const int N = in_sizes[0] / 18;
    const int E = in_sizes[1] / 2;
    const int* src = edge_index;
    const int* dst = edge_index + E;

    // workspace layout (floats):
    // [0, N)        deg -> dis (zeroed)
    // [N, 17N)      agg1 (zeroed)
    // [17N, 18N)    agg2 (zeroed)
    // [18N, 34N)    hs1
    // [34N, 35N)    hs2
    float* ws = (float*)d_ws;
    float* dis = ws;
    float* agg1 = ws + (size_t)N;
    float* agg2 = ws + (size_t)17 * N;
    float* hs1 = ws + (size_t)18 * N;
    float* hs2 = ws + (size_t)34 * N;

    // zero deg + agg1 + agg2 (first 18N floats)
    hipMemsetAsync(d_ws, 0, (size_t)18 * N * sizeof(float), stream);

    int nBlocksE = (E + TPB - 1) / TPB;
    int nBlocksN = (N + TPB - 1) / TPB;

    deg_kernel<<<nBlocksE, TPB, 0, stream>>>(dst, dis, E);
    dis_kernel<<<nBlocksN, TPB, 0, stream>>>(dis, N);
    h1_kernel<<<nBlocksN, TPB, 0, stream>>>(x, W1, dis, hs1, N);
    scatter1_kernel<<<nBlocksE, TPB, 0, stream>>>(src, dst, hs1, agg1, E);
    combine1_kernel<<<nBlocksN, TPB, 0, stream>>>(agg1, hs1, dis, b1, W2, hs2, N);
    scatter2_kernel<<<nBlocksE, TPB, 0, stream>>>(src, dst, hs2, agg2, E);
    combine2_kernel<<<nBlocksN, TPB, 0, stream>>>(agg2, hs2, dis, b2, out, N);
}

// Round 2
// 690.887 us; speedup vs baseline: 5.3963x; 5.3963x over previous
//
#include <hip/hip_runtime.h>

// GCN 2-layer, CSR-gather formulation (no fp atomics).
// N=250000 nodes, E=4000000 edges, 18 -> 16 -> 1.
//
// hs1[n] = (x[n] @ W1) * dis[n]         (dis = rsqrt(deg+1), deg = in-degree)
// layer1: relu(dis[n]*(sum_{s->n} hs1[s] + hs1[n]) + b1)
// hs2[n] = (layer1 @ W2) * dis[n]
// out[n] = dis[n]*(sum_{s->n} hs2[s] + hs2[n]) + b2
//
// CSR built on-device: histogram -> 2-level exclusive scan -> cursor placement.
// After fill, pos[n] = row_end; rows are [pos[n]-deg[n], pos[n]).

#define TPB 256
#define CHUNK 1024  // scan elements per block (256 threads x 4)

__global__ void hist_kernel(const int* __restrict__ dst, int* __restrict__ deg, int E) {
    int e = blockIdx.x * blockDim.x + threadIdx.x;
    if (e < E) atomicAdd(&deg[dst[e]], 1);
}

// per-chunk sums
__global__ void scan1_kernel(const int* __restrict__ deg, int* __restrict__ cs, int N) {
    __shared__ int s[TPB];
    int t = threadIdx.x;
    int base = blockIdx.x * CHUNK + t * 4;
    int sum = 0;
#pragma unroll
    for (int k = 0; k < 4; k++) {
        int i = base + k;
        sum += (i < N) ? deg[i] : 0;
    }
    s[t] = sum;
    __syncthreads();
    for (int off = TPB / 2; off > 0; off >>= 1) {
        if (t < off) s[t] += s[t + off];
        __syncthreads();
    }
    if (t == 0) cs[blockIdx.x] = s[0];
}

// exclusive scan of chunk sums in-place (supports C <= 1024)
__global__ void scan2_kernel(int* __restrict__ cs, int C) {
    __shared__ int s[TPB];
    int t = threadIdx.x;
    int v[4];
    int sum = 0;
#pragma unroll
    for (int k = 0; k < 4; k++) {
        int i = t * 4 + k;
        v[k] = (i < C) ? cs[i] : 0;
        sum += v[k];
    }
    s[t] = sum;
    __syncthreads();
    for (int off = 1; off < TPB; off <<= 1) {
        int add = (t >= off) ? s[t - off] : 0;
        __syncthreads();
        s[t] += add;
        __syncthreads();
    }
    int run = s[t] - sum;  // exclusive
#pragma unroll
    for (int k = 0; k < 4; k++) {
        int i = t * 4 + k;
        if (i < C) cs[i] = run;
        run += v[k];
    }
}

// per-element exclusive scan -> pos (row starts)
__global__ void scan3_kernel(const int* __restrict__ deg, const int* __restrict__ cs,
                             int* __restrict__ pos, int N) {
    __shared__ int s[TPB];
    int t = threadIdx.x;
    int base = blockIdx.x * CHUNK + t * 4;
    int v[4];
    int sum = 0;
#pragma unroll
    for (int k = 0; k < 4; k++) {
        int i = base + k;
        v[k] = (i < N) ? deg[i] : 0;
        sum += v[k];
    }
    s[t] = sum;
    __syncthreads();
    for (int off = 1; off < TPB; off <<= 1) {
        int add = (t >= off) ? s[t - off] : 0;
        __syncthreads();
        s[t] += add;
        __syncthreads();
    }
    int run = cs[blockIdx.x] + s[t] - sum;  // chunk base + thread-exclusive
#pragma unroll
    for (int k = 0; k < 4; k++) {
        int i = base + k;
        if (i < N) pos[i] = run;
        run += v[k];
    }
}

// place edges: pos[dst] cursor-advances from row_start to row_end
__global__ void fill_kernel(const int* __restrict__ src, const int* __restrict__ dst,
                            int* __restrict__ pos, int* __restrict__ csr, int E) {
    int e = blockIdx.x * blockDim.x + threadIdx.x;
    if (e >= E) return;
    int p = atomicAdd(&pos[dst[e]], 1);
    csr[p] = src[e];
}

// hs1[n,f] = (x[n] @ W1)[f] * dis[n]
__global__ void h1_kernel(const float* __restrict__ x, const float* __restrict__ W1,
                          const int* __restrict__ deg, float* __restrict__ hs1, int N) {
    __shared__ float w[18 * 16];
    for (int i = threadIdx.x; i < 18 * 16; i += blockDim.x) w[i] = W1[i];
    __syncthreads();
    int n = blockIdx.x * blockDim.x + threadIdx.x;
    if (n >= N) return;
    float xv[18];
#pragma unroll
    for (int k = 0; k < 18; k++) xv[k] = x[n * 18 + k];
    float d = rsqrtf((float)deg[n] + 1.0f);
    float acc[16];
#pragma unroll
    for (int f = 0; f < 16; f++) acc[f] = 0.0f;
#pragma unroll
    for (int k = 0; k < 18; k++) {
        float xk = xv[k];
#pragma unroll
        for (int f = 0; f < 16; f++) acc[f] = fmaf(xk, w[k * 16 + f], acc[f]);
    }
    float4* out = (float4*)(hs1 + (size_t)n * 16);
#pragma unroll
    for (int q = 0; q < 4; q++) {
        float4 v;
        v.x = acc[q * 4 + 0] * d;
        v.y = acc[q * 4 + 1] * d;
        v.z = acc[q * 4 + 2] * d;
        v.w = acc[q * 4 + 3] * d;
        out[q] = v;
    }
}

// layer-1 aggregate + relu + W2 dot, fused. 4 lanes per node (one float4 quad each).
__global__ void agg1_kernel(const int* __restrict__ csr, const int* __restrict__ pos,
                            const int* __restrict__ deg, const float* __restrict__ hs1,
                            const float* __restrict__ b1, const float* __restrict__ W2,
                            float* __restrict__ hs2, int N) {
    int tid = blockIdx.x * blockDim.x + threadIdx.x;
    int node = tid >> 2;
    int q = tid & 3;
    if (node >= N) return;
    int end = pos[node];
    int dg = deg[node];
    const float4* h4 = (const float4*)hs1;
    float4 acc = make_float4(0.f, 0.f, 0.f, 0.f);
    for (int j = end - dg; j < end; j++) {
        int s = csr[j];
        float4 v = h4[(size_t)s * 4 + q];
        acc.x += v.x; acc.y += v.y; acc.z += v.z; acc.w += v.w;
    }
    float4 self = h4[(size_t)node * 4 + q];
    float d = rsqrtf((float)dg + 1.0f);
    float4 bb = ((const float4*)b1)[q];
    float4 ww = ((const float4*)W2)[q];
    float p = fmaxf(d * (acc.x + self.x) + bb.x, 0.f) * ww.x;
    p      += fmaxf(d * (acc.y + self.y) + bb.y, 0.f) * ww.y;
    p      += fmaxf(d * (acc.z + self.z) + bb.z, 0.f) * ww.z;
    p      += fmaxf(d * (acc.w + self.w) + bb.w, 0.f) * ww.w;
    p += __shfl_xor(p, 1);
    p += __shfl_xor(p, 2);
    if (q == 0) hs2[node] = p * d;
}

// layer-2 aggregate + bias, fused. Thread per node (1 feature).
__global__ void agg2_kernel(const int* __restrict__ csr, const int* __restrict__ pos,
                            const int* __restrict__ deg, const float* __restrict__ hs2,
                            const float* __restrict__ b2, float* __restrict__ out, int N) {
    int n = blockIdx.x * blockDim.x + threadIdx.x;
    if (n >= N) return;
    int end = pos[n];
    int dg = deg[n];
    float acc = 0.f;
    for (int j = end - dg; j < end; j++) acc += hs2[csr[j]];
    float d = rsqrtf((float)dg + 1.0f);
    out[n] = d * (acc + hs2[n]) + b2[0];
}

extern "C" void kernel_launch(void* const* d_in, const int* in_sizes, int n_in,
                              void* d_out, int out_size, void* d_ws, size_t ws_size,
                              hipStream_t stream) {
    const float* x = (const float*)d_in[0];
    const int* edge_index = (const int*)d_in[1];
    const float* W1 = (const float*)d_in[2];
    const float* b1 = (const float*)d_in[3];
    const float* W2 = (const float*)d_in[4];
    const float* b2 = (const float*)d_in[5];
    float* out = (float*)d_out;

    const int N = in_sizes[0] / 18;
    const int E = in_sizes[1] / 2;
    const int* src = edge_index;
    const int* dst = edge_index + E;

    // workspace layout (4B words), total = 19N + E = 35 MB (same as R1, proven fit):
    // [0, N)           deg (int, zeroed)
    // [N, 2N)          pos (int)  -- row starts, becomes row ends after fill
    // [2N, 2N+E)       csr (int)  -- chunk_sums aliases its head (disjoint lifetime)
    // [2N+E, 18N+E)    hs1 (float, 16N)
    // [18N+E, 19N+E)   hs2 (float, N)
    int* ws = (int*)d_ws;
    int* deg = ws;
    int* pos = ws + N;
    int* csr = ws + 2 * (size_t)N;
    int* chunk_sums = csr;  // scan scratch, consumed before csr is written
    float* hs1 = (float*)(ws + 2 * (size_t)N + E);
    float* hs2 = hs1 + 16 * (size_t)N;

    hipMemsetAsync(deg, 0, (size_t)N * sizeof(int), stream);

    int nBlocksE = (E + TPB - 1) / TPB;
    int nBlocksN = (N + TPB - 1) / TPB;
    int C = (N + CHUNK - 1) / CHUNK;  // 245 chunks, scan2 supports <= 1024

    hist_kernel<<<nBlocksE, TPB, 0, stream>>>(dst, deg, E);
    scan1_kernel<<<C, TPB, 0, stream>>>(deg, chunk_sums, N);
    scan2_kernel<<<1, TPB, 0, stream>>>(chunk_sums, C);
    scan3_kernel<<<C, TPB, 0, stream>>>(deg, chunk_sums, pos, N);
    fill_kernel<<<nBlocksE, TPB, 0, stream>>>(src, dst, pos, csr, E);
    h1_kernel<<<nBlocksN, TPB, 0, stream>>>(x, W1, deg, hs1, N);
    agg1_kernel<<<(4 * N + TPB - 1) / TPB, TPB, 0, stream>>>(csr, pos, deg, hs1, b1, W2, hs2, N);
    agg2_kernel<<<nBlocksN, TPB, 0, stream>>>(csr, pos, deg, hs2, b2, out, N);
}